// Round 11
// baseline (331.485 us; speedup 1.0000x reference)
//
#include <hip/hip_runtime.h>
#include <hip/hip_bf16.h>

typedef unsigned short u16;
typedef unsigned int   u32;
typedef short bf16x8 __attribute__((ext_vector_type(8)));
typedef float f32x4  __attribute__((ext_vector_type(4)));

#define O_N    4
#define D_K    128
#define D_V    512
#define BANK   7200
#define NQ     3600
#define NT     64            // query columns per block
#define NTILES 57            // ceil(3600/64)
#define NSUB   225           // 7200 / 32 sub-tiles
#define VH_ROWS 256          // v rows per block (half of 512)

// ---- LDS layout (bytes)
#define K_OFF    0           // K dbuf: 2 x [64 b][128 d] bf16 (2 x 16384)
#define P_OFF    32768       // P dbuf: 2 x [64 n][64 b] bf16, 128B rows (2 x 8192)
#define LMM_OFF  49152       // l[64], mm[64] f32 (512)
#define SMEM_BYTES 49664     // x3 blocks = 146 KB <= 160 KB  -> 3 blocks/CU
#define Q_OFF    0           // Q tile [64 n][128 d] bf16 (16KB) overlaps K buf0; prologue only

// global_load_lds: linear LDS dest (wave base + lane*16); source address is
// pre-permuted per-lane so READ-side swizzle formulas keep working.
// NOTE: imm offset is 13-bit SIGNED (max +4095) — keep 0, explicit addresses.
#define GLL(gsrc, ldst) __builtin_amdgcn_global_load_lds( \
    (const __attribute__((address_space(1))) void*)(gsrc), \
    (__attribute__((address_space(3))) void*)(ldst), 16, 0, 0)

#define MFMA16(a, b, c) __builtin_amdgcn_mfma_f32_16x16x32_bf16((a), (b), (c), 0, 0, 0)

static __device__ __forceinline__ u16 f2bf(float x) {
    u32 u = __builtin_bit_cast(u32, x);
    return (u16)((u + 0x7FFFu + ((u >> 16) & 1u)) >> 16);
}

// Q-side scale fold: stage Q * (log2e / sqrt(128)) so softmax exp becomes a
// bare exp2f (native v_exp_f32), no per-element multiply in the hot loop.
#define QSCALE 0.12751743f

// ---------------- preconv kernels ----------------

__global__ void k_transpose_bf16(const float* __restrict__ in, u16* __restrict__ out) {
    __shared__ float tile[32][33];
    const int obj = blockIdx.z;
    const float* src = in + (size_t)obj * D_K * BANK;
    u16* dst = out + (size_t)obj * BANK * D_K;
    const int bx = blockIdx.x * 32;   // bank
    const int by = blockIdx.y * 32;   // d
    const int tx = threadIdx.x, ty = threadIdx.y;  // 32 x 8
#pragma unroll
    for (int i = 0; i < 4; i++)
        tile[ty + 8 * i][tx] = src[(size_t)(by + ty + 8 * i) * BANK + bx + tx];
    __syncthreads();
#pragma unroll
    for (int i = 0; i < 4; i++)
        dst[(size_t)(bx + ty + 8 * i) * D_K + by + tx] = f2bf(tile[tx][ty + 8 * i]);
}

__global__ void k_convert_bf16(const float* __restrict__ in, u16* __restrict__ out, int n4) {
    int idx = blockIdx.x * blockDim.x + threadIdx.x;
    int stride = gridDim.x * blockDim.x;
    for (int i = idx; i < n4; i += stride) {
        float4 v = reinterpret_cast<const float4*>(in)[i];
        ushort4 o;
        o.x = f2bf(v.x); o.y = f2bf(v.y); o.z = f2bf(v.z); o.w = f2bf(v.w);
        reinterpret_cast<ushort4*>(out)[i] = o;
    }
}

__global__ void k_zero(float* out, int n) {
    int i = blockIdx.x * blockDim.x + threadIdx.x;
    if (i < n) out[i] = 0.f;
}

// ---------------- main fused kernel ----------------
// blockIdx.x = ((tile*G + g) << 3) | (o*2+vh): (o,vh) pinned per XCD for L2.
//
// OCCUPANCY: waves/SIMD = floor(512 / total_regs_per_wave) (per-SIMD file
// 512; steps at 64/128/170/256 — m69, confirmed by R3's 128-cap).
// acc(64) + qf(16) + va/vb(32) + ~45 addressing/temps ≈ 155-165 → fits the
// (256,3) cap of 170 WITHOUT spill → 3 blocks/CU (12 waves) vs R9's 2.
// Register diet vs R9: PV moved to phase TOP so V(u) loads write va/vb
// directly (no na/nb temp set, −32), mv2/mv3 loaded lazily (−8).
//
// ONE barrier per 64-bank unit. Phase u order:
//   [gll K(u+1) — full-phase window] [mv0/1] [PV(u-1) from P_prev, va/vb]
//   [V(u) -> va/vb] [QK(u) -> P_cur, mv2/3 lazy] [vmcnt(0)+lgkmcnt(0), bar]
__launch_bounds__(256, 3)
__global__ void k_matcher(const u16* __restrict__ Kt,     // [O][7200][128] bf16
                          const u16* __restrict__ Vb,     // [O][512][7200] bf16
                          const float* __restrict__ masks,// [O][7200]
                          const float* __restrict__ q_in, // [128][3600]
                          const float* __restrict__ q_out,// [512][3600]
                          float* __restrict__ out,        // [O][1024][3600]
                          int G, float* __restrict__ lw, float* __restrict__ mw)
{
    __shared__ __align__(16) char smem[SMEM_BYTES];
    const int tid  = threadIdx.x;
    const int wave = tid >> 6;
    const int lane = tid & 63;
    const int q    = lane >> 4;
    const int lr   = lane & 15;
    const int lr7  = lr & 7;

    const int grp  = blockIdx.x & 7;
    const int o    = grp >> 1;
    const int vh   = grp & 1;
    const int rest = blockIdx.x >> 3;
    const int tile = rest / G;
    const int g    = rest - tile * G;
    const int n0   = tile * NT;

    // l/mm only consumed via G==1 epilogue or vh==0's lw/mw (G==2)
    const bool needLM = (G == 1) || (vh == 0);

    // sub-tile (32-bank) range for this g; units = doubles (64) + optional tail (32)
    const int st0 = (NSUB * g) / G;
    const int st1 = (NSUB * (g + 1)) / G;
    const int cnt = st1 - st0;
    const int nd  = cnt >> 1;
    const int ts  = cnt & 1;
    const int nu  = nd + ts;

    // ---- stage Q tile (pre-scaled): Q_lds[n][d] bf16, granule swizzle ^ (n&7)
    for (int idx = tid; idx < NT * D_K; idx += 256) {
        int d = idx >> 6;
        int n = idx & 63;
        int gn = n0 + n;
        float v = (gn < NQ) ? q_in[(size_t)d * NQ + gn] * QSCALE : 0.f;
        int bb = d * 2;
        int sb = n * 256 + ((((bb >> 4) ^ (n & 7)) << 4) | (bb & 15));
        *reinterpret_cast<u16*>(smem + Q_OFF + sb) = f2bf(v);
    }
    __syncthreads();

    bf16x8 qf[4];
    {
        const int n = 16 * wave + lr;
#pragma unroll
        for (int ds = 0; ds < 4; ds++) {
            int gq = (4 * ds + q) ^ (n & 7);
            qf[ds] = *reinterpret_cast<const bf16x8*>(smem + Q_OFF + n * 256 + gq * 16);
        }
    }
    __syncthreads();   // Q region about to be overwritten by K staging

    const f32x4 zero4 = {0.f, 0.f, 0.f, 0.f};
    f32x4 acc[4][4];
#pragma unroll
    for (int i = 0; i < 4; i++)
#pragma unroll
        for (int j = 0; j < 4; j++) acc[i][j] = zero4;
    float l_part = 0.f, mm_part = 0.f;

    const u16* Ko = Kt + (size_t)o * BANK * D_K;
    const u16* Vo = Vb + (size_t)o * D_V * BANK + (size_t)vh * VH_ROWS * BANK;
    const float* mPtr = masks + (size_t)o * BANK + st0 * 32 + 4 * q;

    // K gll source pointers, pre-permuted with 4-BIT key: slot s of row b
    // holds granule s ^ (b&15). (row+16k)&15 keeps the same per-lane perm, so
    // +16/+32 row batches are simple pointer offsets.
    const u16* kSrcA = Ko + (size_t)(st0 * 32 + (tid >> 4)) * D_K
                         + (((tid & 15) ^ (tid >> 4)) << 3);
    const u16* kSrcB = kSrcA + 16 * D_K;

#define ISSUE2(buf) do {                                                   \
        char* kb_ = smem + K_OFF + (buf) * 16384 + wave * 1024;            \
        GLL(kSrcA, kb_);                                                   \
        GLL(kSrcB, kb_ + 4096);                                            \
        GLL(kSrcA + 32 * D_K, kb_ + 8192);                                 \
        GLL(kSrcB + 32 * D_K, kb_ + 12288);                                \
        kSrcA += 64 * D_K; kSrcB += 64 * D_K;                              \
    } while (0)
#define ISSUE1(buf) do {                                                   \
        char* kb_ = smem + K_OFF + (buf) * 16384 + wave * 1024;            \
        GLL(kSrcA, kb_);                                                   \
        GLL(kSrcB, kb_ + 4096);                                            \
    } while (0)

    // V direct-to-register: uniform advancing base + per-lane offset.
    const u16* Vrow = Vo + st0 * 32;
    const u32  vOff = (u32)(64 * wave + lr) * BANK + q * 8;

    const int nrow  = 16 * wave + lr;       // this wave's P row

// QK^T for one 16-bank strip T (0..3): 4 MFMA (K read swizzle = 4-bit lr
// key), exp2 (scale pre-folded into Q), optional l/mm, cvt_pk, b64 P write.
#define QK_T(T, MV, PWB) do {                                                \
        f32x4 s_acc = zero4;                                                 \
        const int b_r = 16 * (T) + lr;                                       \
        _Pragma("unroll")                                                    \
        for (int ds = 0; ds < 4; ds++) {                                     \
            bf16x8 kf = *reinterpret_cast<const bf16x8*>(                    \
                kb + b_r * 256 + (((4 * ds + q) ^ lr) << 4));                \
            s_acc = MFMA16(kf, qf[ds], s_acc);                               \
        }                                                                    \
        float p0 = exp2f(s_acc[0]);                                          \
        float p1 = exp2f(s_acc[1]);                                          \
        float p2 = exp2f(s_acc[2]);                                          \
        float p3 = exp2f(s_acc[3]);                                          \
        if (needLM) {                                                        \
            l_part  += p0 + p1 + p2 + p3;                                    \
            mm_part += p0 * (MV).x + p1 * (MV).y + p2 * (MV).z + p3 * (MV).w;\
        }                                                                    \
        u32 w0, w1;                                                          \
        asm("v_cvt_pk_bf16_f32 %0, %1, %2" : "=v"(w0) : "v"(p0), "v"(p1));   \
        asm("v_cvt_pk_bf16_f32 %0, %1, %2" : "=v"(w1) : "v"(p2), "v"(p3));   \
        uint2 pk2; pk2.x = w0; pk2.y = w1;                                   \
        *reinterpret_cast<uint2*>(                                           \
            (PWB) + (((2 * (T) + (q >> 1)) ^ lr7) << 4)) = pk2;              \
    } while (0)

// PV for one 32-bank sub S from P buffer PB with V frags V0..V3
#define PV_S(S, PB, V0, V1, V2, V3) do {                                     \
        _Pragma("unroll")                                                    \
        for (int ng = 0; ng < 4; ng++) {                                     \
            bf16x8 pf = *reinterpret_cast<const bf16x8*>(                    \
                (PB) + (16 * ng + lr) * 128 +                                \
                (((4 * (S) + q) ^ lr7) << 4));                               \
            acc[0][ng] = MFMA16(V0, pf, acc[0][ng]);                         \
            acc[1][ng] = MFMA16(V1, pf, acc[1][ng]);                         \
            acc[2][ng] = MFMA16(V2, pf, acc[2][ng]);                         \
            acc[3][ng] = MFMA16(V3, pf, acc[3][ng]);                         \
        }                                                                    \
    } while (0)

    // ---- prologue: stage unit 0, wait, barrier
    if (nd > 0) ISSUE2(0); else ISSUE1(0);
    asm volatile("s_waitcnt vmcnt(0)" ::: "memory");
    __builtin_amdgcn_s_barrier();
    __builtin_amdgcn_sched_barrier(0);

    bf16x8 va0, va1, va2, va3, vb0, vb1, vb2, vb3;

    for (int u = 0; u < nu; u++) {
        const int cur = u & 1;
        const char* kb = smem + K_OFF + cur * 16384;
        char* pWc = smem + P_OFF + cur * 8192 + nrow * 128 + (q & 1) * 8;
        const char* pR = smem + P_OFF + (cur ^ 1) * 8192;
        const bool full = (u < nd);

        // ---- K staging for unit u+1 at TOP: full-phase latency window
        if (u + 1 < nu) {
            if (u + 1 < nd) ISSUE2(cur ^ 1);
            else            ISSUE1(cur ^ 1);
        }
        // masks for strips 0,1 (tiny, L2-hot) — issued early
        float4 mv0 = *reinterpret_cast<const float4*>(mPtr);
        float4 mv1 = *reinterpret_cast<const float4*>(mPtr + 16);
        __builtin_amdgcn_sched_barrier(0);

        // ---- PV(u-1) from P[prev] with va/vb loaded LAST phase
        if (u > 0) {
            PV_S(0, pR, va0, va1, va2, va3);
            PV_S(1, pR, vb0, vb1, vb2, vb3);
        }
        __builtin_amdgcn_sched_barrier(0);   // pin: V loads AFTER PV consumed va/vb
                                             // (register reuse, not rename — keeps
                                             // pressure under the 170 cap)

        // ---- V(u) straight into va/vb (consumed next phase / epilogue);
        // latency window = QK(u) below, drained by the end-of-phase fence.
        va0 = *reinterpret_cast<const bf16x8*>(Vrow + vOff);
        va1 = *reinterpret_cast<const bf16x8*>(Vrow + vOff + 16 * BANK);
        va2 = *reinterpret_cast<const bf16x8*>(Vrow + vOff + 32 * BANK);
        va3 = *reinterpret_cast<const bf16x8*>(Vrow + vOff + 48 * BANK);
        if (full) {
            vb0 = *reinterpret_cast<const bf16x8*>(Vrow + vOff + 32);
            vb1 = *reinterpret_cast<const bf16x8*>(Vrow + vOff + 32 + 16 * BANK);
            vb2 = *reinterpret_cast<const bf16x8*>(Vrow + vOff + 32 + 32 * BANK);
            vb3 = *reinterpret_cast<const bf16x8*>(Vrow + vOff + 32 + 48 * BANK);
        }

        // ---- QK(u) into P[cur]; mv2/mv3 loaded lazily (short live range)
        QK_T(0, mv0, pWc);
        QK_T(1, mv1, pWc);
        if (full) {
            float4 mv2 = *reinterpret_cast<const float4*>(mPtr + 32);
            float4 mv3 = *reinterpret_cast<const float4*>(mPtr + 48);
            QK_T(2, mv2, pWc);
            QK_T(3, mv3, pWc);
        }

        mPtr += full ? 64 : 32;
        Vrow += full ? 64 : 32;

        // ---- end fence: gll(u+1) + V(u) done, P[cur] visible
        asm volatile("s_waitcnt vmcnt(0) lgkmcnt(0)" ::: "memory");
        __builtin_amdgcn_s_barrier();
        __builtin_amdgcn_sched_barrier(0);
    }

    // ---- epilogue PV for the last unit
    {
        const char* pL = smem + P_OFF + ((nu - 1) & 1) * 8192;
        PV_S(0, pL, va0, va1, va2, va3);
        if (!ts) PV_S(1, pL, vb0, vb1, vb2, vb3);
    }

    // ---- finalize l, mm
    float* l_lds  = reinterpret_cast<float*>(smem + LMM_OFF);
    float* mm_lds = l_lds + 64;
    if (needLM) {
        l_part  += __shfl_xor(l_part, 16);  l_part  += __shfl_xor(l_part, 32);
        mm_part += __shfl_xor(mm_part, 16); mm_part += __shfl_xor(mm_part, 32);
        if (lane < 16) {
            l_lds[16 * wave + lr]  = l_part;
            mm_lds[16 * wave + lr] = mm_part;
        }
    }
    __syncthreads();

    if (G == 1) {
        // ---- final epilogue: mem = acc/l ; gated = q_out * (mm/l)
        float* outo = out + (size_t)o * (1024 * NQ);
#pragma unroll
        for (int ng = 0; ng < 4; ng++) {
            const int n  = 16 * ng + lr;
            const int gn = n0 + n;
            if (gn >= NQ) continue;
            const float invl = 1.f / l_lds[n];
            const float gate = mm_lds[n] * invl;
#pragma unroll
            for (int vt = 0; vt < 4; vt++) {
#pragma unroll
                for (int r = 0; r < 4; r++) {
                    const int v = vh * VH_ROWS + 64 * wave + 16 * vt + 4 * q + r;
                    outo[(size_t)v * NQ + gn] = acc[vt][ng][r] * invl;
                    outo[(size_t)(512 + v) * NQ + gn] = q_out[(size_t)v * NQ + gn] * gate;
                }
            }
        }
    } else {
        // ---- partial epilogue: raw acc into out rows [g*512 .. g*512+511]
        float* dst = out + ((size_t)o * 1024 + (size_t)g * 512 + (size_t)vh * VH_ROWS) * NQ;
#pragma unroll
        for (int ng = 0; ng < 4; ng++) {
            const int n  = 16 * ng + lr;
            const int gn = n0 + n;
            if (gn >= NQ) continue;
#pragma unroll
            for (int vt = 0; vt < 4; vt++) {
#pragma unroll
                for (int r = 0; r < 4; r++) {
                    const int v = 64 * wave + 16 * vt + 4 * q + r;
                    dst[(size_t)v * NQ + gn] = acc[vt][ng][r];
                }
            }
        }
        if (vh == 0 && tid < 64) {
            const size_t li = ((size_t)(g * 4 + o) * NTILES + tile) * 64 + tid;
            lw[li] = l_lds[tid];
            mw[li] = mm_lds[tid];
        }
    }
}

// ---------------- combine pass (G=2) ----------------
__global__ void k_combine(const float* __restrict__ q_out, const float* __restrict__ lw,
                          const float* __restrict__ mw, float* __restrict__ out) {
    const int total = O_N * 512 * (NQ / 4);   // float4 elements per half-row set
    float4* outv = reinterpret_cast<float4*>(out);
    const float4* qv = reinterpret_cast<const float4*>(q_out);
    for (int idx = blockIdx.x * blockDim.x + threadIdx.x; idx < total;
         idx += gridDim.x * blockDim.x) {
        const int o  = idx / (512 * 900);
        const int r  = idx - o * 512 * 900;
        const int v  = r / 900;
        const int g4 = r - v * 900;
        const size_t iA = ((size_t)o * 1024 + v) * 900 + g4;
        const size_t iB = ((size_t)o * 1024 + 512 + v) * 900 + g4;
        float4 A = outv[iA];
        float4 B = outv[iB];
        const int tl = g4 >> 4;
        const int wi = (g4 & 15) * 4;
        const size_t l0i = ((size_t)(0 * 4 + o) * NTILES + tl) * 64 + wi;
        const size_t l1i = ((size_t)(1 * 4 + o) * NTILES + tl) * 64 + wi;
        const float4 l0 = *reinterpret_cast<const float4*>(lw + l0i);
        const float4 l1 = *reinterpret_cast<const float4*>(lw + l1i);
        const float4 m0 = *reinterpret_cast<const float4*>(mw + l0i);
        const float4 m1 = *reinterpret_cast<const float4*>(mw + l1i);
        float4 li, mem, gate;
        li.x = 1.f / (l0.x + l1.x); li.y = 1.f / (l0.y + l1.y);
        li.z = 1.f / (l0.z + l1.z); li.w = 1.f / (l0.w + l1.w);
        mem.x = (A.x + B.x) * li.x; mem.y = (A.y + B.y) * li.y;
        mem.z = (A.z + B.z) * li.z; mem.w = (A.w + B.w) * li.w;
        gate.x = (m0.x + m1.x) * li.x; gate.y = (m0.y + m1.y) * li.y;
        gate.z = (m0.z + m1.z) * li.z; gate.w = (m0.w + m1.w) * li.w;
        float4 qo = qv[(size_t)v * 900 + g4];
        outv[iA] = mem;
        float4 gq;
        gq.x = qo.x * gate.x; gq.y = qo.y * gate.y;
        gq.z = qo.z * gate.z; gq.w = qo.w * gate.w;
        outv[iB] = gq;
    }
}

extern "C" void kernel_launch(void* const* d_in, const int* in_sizes, int n_in,
                              void* d_out, int out_size, void* d_ws, size_t ws_size,
                              hipStream_t stream) {
    const float* keys   = (const float*)d_in[0];
    const float* values = (const float*)d_in[1];
    const float* masks  = (const float*)d_in[2];
    const float* q_in   = (const float*)d_in[3];
    const float* q_outp = (const float*)d_in[4];
    float* out = (float*)d_out;

    const size_t K_BYTES  = (size_t)O_N * BANK * D_K * 2;   //  7,372,800
    const size_t V_BYTES  = (size_t)O_N * D_V * BANK * 2;   // 29,491,200
    const size_t LM_FLOATS = (size_t)2 * O_N * NTILES * 64; // per array (G=2)
    const size_t LM_BYTES  = LM_FLOATS * 4 * 2;             // l + mm

    if (ws_size < K_BYTES + V_BYTES) {
        k_zero<<<(out_size + 255) / 256, 256, 0, stream>>>(out, out_size);
        return;
    }
    const int G = (ws_size >= K_BYTES + V_BYTES + LM_BYTES) ? 2 : 1;

    u16* Kt = (u16*)d_ws;
    u16* Vb = (u16*)((char*)d_ws + K_BYTES);
    float* lw = (float*)((char*)d_ws + K_BYTES + V_BYTES);
    float* mw = lw + LM_FLOATS;

    dim3 tb(32, 8);
    dim3 tg(BANK / 32, D_K / 32, O_N);
    k_transpose_bf16<<<tg, tb, 0, stream>>>(keys, Kt);

    const int n4 = O_N * D_V * BANK / 4;
    k_convert_bf16<<<2048, 256, 0, stream>>>(values, Vb, n4);

    k_matcher<<<NTILES * 8 * G, 256, 0, stream>>>(Kt, Vb, masks, q_in, q_outp, out,
                                                  G, lw, mw);
    if (G == 2)
        k_combine<<<2048, 256, 0, stream>>>(q_outp, lw, mw, out);
}

// Round 12
// 289.242 us; speedup vs baseline: 1.1460x; 1.1460x over previous
//
#include <hip/hip_runtime.h>
#include <hip/hip_bf16.h>

typedef unsigned short u16;
typedef unsigned int   u32;
typedef short bf16x8 __attribute__((ext_vector_type(8)));
typedef float f32x4  __attribute__((ext_vector_type(4)));

#define O_N    4
#define D_K    128
#define D_V    512
#define BANK   7200
#define NQ     3600
#define NT     64            // query columns per block
#define NTILES 57            // ceil(3600/64)
#define NSUB   225           // 7200 / 32 sub-tiles
#define VH_ROWS 256          // v rows per block (half of 512)

// ---- LDS layout (bytes). K is NOT staged in LDS anymore (global->reg like V):
// per-unit LDS traffic drops 120KB -> 40KB (P exchange only).
#define P_OFF    0           // P dbuf: 2 x [64 n][64 b] bf16, 128B rows (2 x 8192)
#define LST_OFF  16384       // l stage [4 waves][64 n] f32 (1024)
#define MST_OFF  17408       // mm stage [4][64] f32 (1024)
#define SMEM_BYTES 18432
#define Q_OFF    0           // Q tile [64 n][128 d] bf16 (16KB) overlaps P dbuf; prologue only

#define MFMA16(a, b, c) __builtin_amdgcn_mfma_f32_16x16x32_bf16((a), (b), (c), 0, 0, 0)

static __device__ __forceinline__ u16 f2bf(float x) {
    u32 u = __builtin_bit_cast(u32, x);
    return (u16)((u + 0x7FFFu + ((u >> 16) & 1u)) >> 16);
}

// Q-side scale fold: stage Q * (log2e / sqrt(128)) so softmax exp is bare exp2f.
#define QSCALE 0.12751743f

// ---------------- preconv kernels ----------------

__global__ void k_transpose_bf16(const float* __restrict__ in, u16* __restrict__ out) {
    __shared__ float tile[32][33];
    const int obj = blockIdx.z;
    const float* src = in + (size_t)obj * D_K * BANK;
    u16* dst = out + (size_t)obj * BANK * D_K;
    const int bx = blockIdx.x * 32;   // bank
    const int by = blockIdx.y * 32;   // d
    const int tx = threadIdx.x, ty = threadIdx.y;  // 32 x 8
#pragma unroll
    for (int i = 0; i < 4; i++)
        tile[ty + 8 * i][tx] = src[(size_t)(by + ty + 8 * i) * BANK + bx + tx];
    __syncthreads();
#pragma unroll
    for (int i = 0; i < 4; i++)
        dst[(size_t)(bx + ty + 8 * i) * D_K + by + tx] = f2bf(tile[tx][ty + 8 * i]);
}

__global__ void k_convert_bf16(const float* __restrict__ in, u16* __restrict__ out, int n4) {
    int idx = blockIdx.x * blockDim.x + threadIdx.x;
    int stride = gridDim.x * blockDim.x;
    for (int i = idx; i < n4; i += stride) {
        float4 v = reinterpret_cast<const float4*>(in)[i];
        ushort4 o;
        o.x = f2bf(v.x); o.y = f2bf(v.y); o.z = f2bf(v.z); o.w = f2bf(v.w);
        reinterpret_cast<ushort4*>(out)[i] = o;
    }
}

__global__ void k_zero(float* out, int n) {
    int i = blockIdx.x * blockDim.x + threadIdx.x;
    if (i < n) out[i] = 0.f;
}

// ---------------- main fused kernel ----------------
// blockIdx.x = ((tile*G + g) << 3) | (o*2+vh): (o,vh) pinned per XCD for L2.
//
// QK is split by BANKS across waves (wave w owns banks 16w..16w+15 of each
// 64-bank unit) so K loads straight into registers (like V) — no K LDS at
// all. Q fragments for ALL 64 columns live in registers (qf[4][4], 64 VGPR).
// Per-unit LDS traffic: P-write 8KB + P-read 32KB only.
//
// Sync: ONE barrier per unit with lgkmcnt(0) ONLY (P visibility). No vmcnt
// fences anywhere — K/V register loads are drained by compiler-counted
// waits at their consumers (K covered by PV(u-1), V by QK(u)+barrier).
//
// Output C/D mapping per MFMA: col = lane&15, row = 4*(lane>>4)+reg.
// QK: lane holds S[bank = ub+16w+4q+r][n = 16cg+lr] -> P write is a
// contiguous ushort4 at P[n][granule 2w+(q>>1), half q&1] — bijective over
// (w,q); PV read side is unchanged from the verified kernel.
__launch_bounds__(256, 2)
__global__ void k_matcher(const u16* __restrict__ Kt,     // [O][7200][128] bf16
                          const u16* __restrict__ Vb,     // [O][512][7200] bf16
                          const float* __restrict__ masks,// [O][7200]
                          const float* __restrict__ q_in, // [128][3600]
                          const float* __restrict__ q_out,// [512][3600]
                          float* __restrict__ out,        // [O][1024][3600]
                          int G, float* __restrict__ lw, float* __restrict__ mw)
{
    __shared__ __align__(16) char smem[SMEM_BYTES];
    const int tid  = threadIdx.x;
    const int wave = tid >> 6;
    const int lane = tid & 63;
    const int q    = lane >> 4;
    const int lr   = lane & 15;
    const int lr7  = lr & 7;

    const int grp  = blockIdx.x & 7;
    const int o    = grp >> 1;
    const int vh   = grp & 1;
    const int rest = blockIdx.x >> 3;
    const int tile = rest / G;
    const int g    = rest - tile * G;
    const int n0   = tile * NT;

    const bool needLM = (G == 1) || (vh == 0);

    // sub-tile (32-bank) range; units = doubles (64 banks) + optional 32-bank tail
    const int st0 = (NSUB * g) / G;
    const int st1 = (NSUB * (g + 1)) / G;
    const int cnt = st1 - st0;
    const int nd  = cnt >> 1;
    const int ts  = cnt & 1;
    const int nu  = nd + ts;

    // ---- stage Q tile (pre-scaled): Q_lds[n][d] bf16, granule swizzle ^ (n&7)
    for (int idx = tid; idx < NT * D_K; idx += 256) {
        int d = idx >> 6;
        int n = idx & 63;
        int gn = n0 + n;
        float v = (gn < NQ) ? q_in[(size_t)d * NQ + gn] * QSCALE : 0.f;
        int bb = d * 2;
        int sb = n * 256 + ((((bb >> 4) ^ (n & 7)) << 4) | (bb & 15));
        *reinterpret_cast<u16*>(smem + Q_OFF + sb) = f2bf(v);
    }
    __syncthreads();

    // ---- Q fragments for ALL 4 column groups (qf[cg][ds], 64 VGPRs)
    bf16x8 qf[4][4];
#pragma unroll
    for (int cg = 0; cg < 4; cg++)
#pragma unroll
        for (int ds = 0; ds < 4; ds++) {
            int gq = (4 * ds + q) ^ lr7;   // (16cg+lr)&7 == lr7
            qf[cg][ds] = *reinterpret_cast<const bf16x8*>(
                smem + Q_OFF + (16 * cg + lr) * 256 + gq * 16);
        }
    __syncthreads();   // Q region about to be overwritten by P tiles

    const f32x4 zero4 = {0.f, 0.f, 0.f, 0.f};
    f32x4 acc[4][4];
#pragma unroll
    for (int i = 0; i < 4; i++)
#pragma unroll
        for (int j = 0; j < 4; j++) acc[i][j] = zero4;
    float l_part[4]  = {0.f, 0.f, 0.f, 0.f};
    float mm_part[4] = {0.f, 0.f, 0.f, 0.f};

    const u16* Ko = Kt + (size_t)o * BANK * D_K;
    const u16* Vo = Vb + (size_t)o * D_V * BANK + (size_t)vh * VH_ROWS * BANK;

    // K direct-to-register: uniform advancing base + per-lane offset.
    // Lane reads K[ub + 16*wave + lr][32*ds + 8*q .. +7] (16B, ds imm-folded).
    const u16* Krow = Ko + (size_t)(st0 * 32) * D_K;
    const u32  kOff = (u32)(16 * wave + lr) * D_K + q * 8;

    // V direct-to-register (unchanged): wave owns v rows [64w, 64w+64).
    const u16* Vrow = Vo + st0 * 32;
    const u32  vOff = (u32)(64 * wave + lr) * BANK + q * 8;

    // mask: lane's banks are ub + 16*wave + 4*q + r (r=0..3)
    const float* mPtr = masks + (size_t)o * BANK + st0 * 32 + 16 * wave + 4 * q;

// QK for one column group CG: 4 MFMA over d, exp2, l/mm, cvt_pk, b64 P write.
#define QK_CG(CG) do {                                                       \
        f32x4 s_acc = zero4;                                                 \
        s_acc = MFMA16(kf0, qf[CG][0], s_acc);                               \
        s_acc = MFMA16(kf1, qf[CG][1], s_acc);                               \
        s_acc = MFMA16(kf2, qf[CG][2], s_acc);                               \
        s_acc = MFMA16(kf3, qf[CG][3], s_acc);                               \
        float p0 = exp2f(s_acc[0]);                                          \
        float p1 = exp2f(s_acc[1]);                                          \
        float p2 = exp2f(s_acc[2]);                                          \
        float p3 = exp2f(s_acc[3]);                                          \
        if (needLM) {                                                        \
            l_part[CG]  += p0 + p1 + p2 + p3;                                \
            mm_part[CG] += p0 * mv.x + p1 * mv.y + p2 * mv.z + p3 * mv.w;    \
        }                                                                    \
        u32 w0, w1;                                                          \
        asm("v_cvt_pk_bf16_f32 %0, %1, %2" : "=v"(w0) : "v"(p0), "v"(p1));   \
        asm("v_cvt_pk_bf16_f32 %0, %1, %2" : "=v"(w1) : "v"(p2), "v"(p3));   \
        uint2 pk2; pk2.x = w0; pk2.y = w1;                                   \
        *reinterpret_cast<uint2*>(pWb + (16 * (CG) + lr) * 128 +             \
            (((2 * wave + (q >> 1)) ^ lr7) << 4) + (q & 1) * 8) = pk2;       \
    } while (0)

// PV for one 32-bank sub S from P buffer PB with V frags V0..V3 (unchanged)
#define PV_S(S, PB, V0, V1, V2, V3) do {                                     \
        _Pragma("unroll")                                                    \
        for (int ng = 0; ng < 4; ng++) {                                     \
            bf16x8 pf = *reinterpret_cast<const bf16x8*>(                    \
                (PB) + (16 * ng + lr) * 128 +                                \
                (((4 * (S) + q) ^ lr7) << 4));                               \
            acc[0][ng] = MFMA16(V0, pf, acc[0][ng]);                         \
            acc[1][ng] = MFMA16(V1, pf, acc[1][ng]);                         \
            acc[2][ng] = MFMA16(V2, pf, acc[2][ng]);                         \
            acc[3][ng] = MFMA16(V3, pf, acc[3][ng]);                         \
        }                                                                    \
    } while (0)

    bf16x8 va0, va1, va2, va3, vb0, vb1, vb2, vb3;

    for (int u = 0; u < nu; u++) {
        const int cur = u & 1;
        char* pWb = smem + P_OFF + cur * 8192;
        const char* pR = smem + P_OFF + (cur ^ 1) * 8192;
        const bool full = (u < nd);
        const bool doQK = full || (wave < 2);   // tail unit: 32 banks = waves 0,1

        // ---- 1) issue K(u) frags + mask (kf dead since last phase's QK)
        bf16x8 kf0, kf1, kf2, kf3;
        float4 mv;
        if (doQK) {
            kf0 = *reinterpret_cast<const bf16x8*>(Krow + kOff);
            kf1 = *reinterpret_cast<const bf16x8*>(Krow + kOff + 32);
            kf2 = *reinterpret_cast<const bf16x8*>(Krow + kOff + 64);
            kf3 = *reinterpret_cast<const bf16x8*>(Krow + kOff + 96);
            mv  = *reinterpret_cast<const float4*>(mPtr);
        }
        __builtin_amdgcn_sched_barrier(0);

        // ---- 2) PV(u-1) from P[prev] — covers K load latency
        if (u > 0) {
            PV_S(0, pR, va0, va1, va2, va3);
            PV_S(1, pR, vb0, vb1, vb2, vb3);
        }
        __builtin_amdgcn_sched_barrier(0);   // V loads below reuse va/vb regs

        // ---- 3) issue V(u) into va/vb (consumed next phase; QK+barrier cover)
        va0 = *reinterpret_cast<const bf16x8*>(Vrow + vOff);
        va1 = *reinterpret_cast<const bf16x8*>(Vrow + vOff + 16 * BANK);
        va2 = *reinterpret_cast<const bf16x8*>(Vrow + vOff + 32 * BANK);
        va3 = *reinterpret_cast<const bf16x8*>(Vrow + vOff + 48 * BANK);
        if (full) {
            vb0 = *reinterpret_cast<const bf16x8*>(Vrow + vOff + 32);
            vb1 = *reinterpret_cast<const bf16x8*>(Vrow + vOff + 32 + 16 * BANK);
            vb2 = *reinterpret_cast<const bf16x8*>(Vrow + vOff + 32 + 32 * BANK);
            vb3 = *reinterpret_cast<const bf16x8*>(Vrow + vOff + 32 + 48 * BANK);
        }

        // ---- 4) QK(u): S[wave's 16 banks][all 64 cols] -> P[cur]
        if (doQK) {
            QK_CG(0); QK_CG(1); QK_CG(2); QK_CG(3);
        }

        Vrow += full ? 64 : 32;
        Krow += (full ? 64 : 32) * D_K;
        mPtr += full ? 64 : 32;

        // ---- end fence: P[cur] writes + P[prev]/LDS reads done. NO vmcnt —
        // V loads stay in flight across the barrier.
        asm volatile("s_waitcnt lgkmcnt(0)" ::: "memory");
        __builtin_amdgcn_s_barrier();
        __builtin_amdgcn_sched_barrier(0);
    }

    // ---- epilogue PV for the last unit
    {
        const char* pL = smem + P_OFF + ((nu - 1) & 1) * 8192;
        PV_S(0, pL, va0, va1, va2, va3);
        if (!ts) PV_S(1, pL, vb0, vb1, vb2, vb3);
    }

    // ---- l/mm: reduce over q within wave, stage per wave, sum across waves
    float* lst = reinterpret_cast<float*>(smem + LST_OFF);  // [4][64]
    float* mst = reinterpret_cast<float*>(smem + MST_OFF);  // [4][64]
    if (needLM) {
#pragma unroll
        for (int cg = 0; cg < 4; cg++) {
            l_part[cg]  += __shfl_xor(l_part[cg], 16);
            l_part[cg]  += __shfl_xor(l_part[cg], 32);
            mm_part[cg] += __shfl_xor(mm_part[cg], 16);
            mm_part[cg] += __shfl_xor(mm_part[cg], 32);
        }
        if (lane < 16) {
#pragma unroll
            for (int cg = 0; cg < 4; cg++) {
                lst[wave * 64 + 16 * cg + lr] = l_part[cg];
                mst[wave * 64 + 16 * cg + lr] = mm_part[cg];
            }
        }
    }
    __syncthreads();

    if (G == 1) {
        // ---- final epilogue: mem = acc/l ; gated = q_out * (mm/l)
        float* outo = out + (size_t)o * (1024 * NQ);
#pragma unroll
        for (int ng = 0; ng < 4; ng++) {
            const int n  = 16 * ng + lr;
            const int gn = n0 + n;
            if (gn >= NQ) continue;
            const float lsum = lst[n] + lst[64 + n] + lst[128 + n] + lst[192 + n];
            const float msum = mst[n] + mst[64 + n] + mst[128 + n] + mst[192 + n];
            const float invl = 1.f / lsum;
            const float gate = msum * invl;
#pragma unroll
            for (int vt = 0; vt < 4; vt++) {
#pragma unroll
                for (int r = 0; r < 4; r++) {
                    const int v = vh * VH_ROWS + 64 * wave + 16 * vt + 4 * q + r;
                    outo[(size_t)v * NQ + gn] = acc[vt][ng][r] * invl;
                    outo[(size_t)(512 + v) * NQ + gn] = q_out[(size_t)v * NQ + gn] * gate;
                }
            }
        }
    } else {
        // ---- partial epilogue: raw acc into out rows [g*512 .. g*512+511]
        float* dst = out + ((size_t)o * 1024 + (size_t)g * 512 + (size_t)vh * VH_ROWS) * NQ;
#pragma unroll
        for (int ng = 0; ng < 4; ng++) {
            const int n  = 16 * ng + lr;
            const int gn = n0 + n;
            if (gn >= NQ) continue;
#pragma unroll
            for (int vt = 0; vt < 4; vt++) {
#pragma unroll
                for (int r = 0; r < 4; r++) {
                    const int v = 64 * wave + 16 * vt + 4 * q + r;
                    dst[(size_t)v * NQ + gn] = acc[vt][ng][r];
                }
            }
        }
        if (vh == 0 && tid < 64) {
            const size_t li = ((size_t)(g * 4 + o) * NTILES + tile) * 64 + tid;
            lw[li] = lst[tid] + lst[64 + tid] + lst[128 + tid] + lst[192 + tid];
            mw[li] = mst[tid] + mst[64 + tid] + mst[128 + tid] + mst[192 + tid];
        }
    }
}

// ---------------- combine pass (G=2) ----------------
__global__ void k_combine(const float* __restrict__ q_out, const float* __restrict__ lw,
                          const float* __restrict__ mw, float* __restrict__ out) {
    const int total = O_N * 512 * (NQ / 4);   // float4 elements per half-row set
    float4* outv = reinterpret_cast<float4*>(out);
    const float4* qv = reinterpret_cast<const float4*>(q_out);
    for (int idx = blockIdx.x * blockDim.x + threadIdx.x; idx < total;
         idx += gridDim.x * blockDim.x) {
        const int o  = idx / (512 * 900);
        const int r  = idx - o * 512 * 900;
        const int v  = r / 900;
        const int g4 = r - v * 900;
        const size_t iA = ((size_t)o * 1024 + v) * 900 + g4;
        const size_t iB = ((size_t)o * 1024 + 512 + v) * 900 + g4;
        float4 A = outv[iA];
        float4 B = outv[iB];
        const int tl = g4 >> 4;
        const int wi = (g4 & 15) * 4;
        const size_t l0i = ((size_t)(0 * 4 + o) * NTILES + tl) * 64 + wi;
        const size_t l1i = ((size_t)(1 * 4 + o) * NTILES + tl) * 64 + wi;
        const float4 l0 = *reinterpret_cast<const float4*>(lw + l0i);
        const float4 l1 = *reinterpret_cast<const float4*>(lw + l1i);
        const float4 m0 = *reinterpret_cast<const float4*>(mw + l0i);
        const float4 m1 = *reinterpret_cast<const float4*>(mw + l1i);
        float4 li, mem, gate;
        li.x = 1.f / (l0.x + l1.x); li.y = 1.f / (l0.y + l1.y);
        li.z = 1.f / (l0.z + l1.z); li.w = 1.f / (l0.w + l1.w);
        mem.x = (A.x + B.x) * li.x; mem.y = (A.y + B.y) * li.y;
        mem.z = (A.z + B.z) * li.z; mem.w = (A.w + B.w) * li.w;
        gate.x = (m0.x + m1.x) * li.x; gate.y = (m0.y + m1.y) * li.y;
        gate.z = (m0.z + m1.z) * li.z; gate.w = (m0.w + m1.w) * li.w;
        float4 qo = qv[(size_t)v * 900 + g4];
        outv[iA] = mem;
        float4 gq;
        gq.x = qo.x * gate.x; gq.y = qo.y * gate.y;
        gq.z = qo.z * gate.z; gq.w = qo.w * gate.w;
        outv[iB] = gq;
    }
}

extern "C" void kernel_launch(void* const* d_in, const int* in_sizes, int n_in,
                              void* d_out, int out_size, void* d_ws, size_t ws_size,
                              hipStream_t stream) {
    const float* keys   = (const float*)d_in[0];
    const float* values = (const float*)d_in[1];
    const float* masks  = (const float*)d_in[2];
    const float* q_in   = (const float*)d_in[3];
    const float* q_outp = (const float*)d_in[4];
    float* out = (float*)d_out;

    const size_t K_BYTES  = (size_t)O_N * BANK * D_K * 2;   //  7,372,800
    const size_t V_BYTES  = (size_t)O_N * D_V * BANK * 2;   // 29,491,200
    const size_t LM_FLOATS = (size_t)2 * O_N * NTILES * 64; // per array (G=2)
    const size_t LM_BYTES  = LM_FLOATS * 4 * 2;             // l + mm

    if (ws_size < K_BYTES + V_BYTES) {
        k_zero<<<(out_size + 255) / 256, 256, 0, stream>>>(out, out_size);
        return;
    }
    const int G = (ws_size >= K_BYTES + V_BYTES + LM_BYTES) ? 2 : 1;

    u16* Kt = (u16*)d_ws;
    u16* Vb = (u16*)((char*)d_ws + K_BYTES);
    float* lw = (float*)((char*)d_ws + K_BYTES + V_BYTES);
    float* mw = lw + LM_FLOATS;

    dim3 tb(32, 8);
    dim3 tg(BANK / 32, D_K / 32, O_N);
    k_transpose_bf16<<<tg, tb, 0, stream>>>(keys, Kt);

    const int n4 = O_N * D_V * BANK / 4;
    k_convert_bf16<<<2048, 256, 0, stream>>>(values, Vb, n4);

    k_matcher<<<NTILES * 8 * G, 256, 0, stream>>>(Kt, Vb, masks, q_in, q_outp, out,
                                                  G, lw, mw);
    if (G == 2)
        k_combine<<<2048, 256, 0, stream>>>(q_outp, lw, mw, out);
}